// Round 15
// baseline (111.230 us; speedup 1.0000x reference)
//
#include <hip/hip_runtime.h>
#include <hip/hip_bf16.h>
#include <math.h>

#define NTOK  16384
#define INF   2048
#define OUTF  2048
#define SR    45
#define RANK  8
#define BLK   64
#define NBLK  32
#define NRULE 256
#define NHIST 32
#define MAXSLOT (NTOK + NRULE * 15)   // 20224
#define NTILE16 (MAXSLOT / 16)        // 1264 tiles of 16 slots

typedef __attribute__((ext_vector_type(8))) short bf16x8;
typedef __attribute__((ext_vector_type(4))) float f32x4;
typedef __attribute__((ext_vector_type(4))) short s16x4;

typedef const __attribute__((address_space(1))) unsigned int GU32;
typedef __attribute__((address_space(3))) unsigned int LU32;

#define MFMA __builtin_amdgcn_mfma_f32_16x16x32_bf16
#define SBAR() __builtin_amdgcn_sched_barrier(0)

__device__ inline short f2bs(float f) {
    __hip_bfloat16 h = __float2bfloat16(f);
    return *reinterpret_cast<short*>(&h);
}
__device__ inline bf16x8 cvt8(const float4& a, const float4& b) {
    bf16x8 r;
    r[0] = f2bs(a.x); r[1] = f2bs(a.y); r[2] = f2bs(a.z); r[3] = f2bs(a.w);
    r[4] = f2bs(b.x); r[5] = f2bs(b.y); r[6] = f2bs(b.z); r[7] = f2bs(b.w);
    return r;
}

// ---------------------------------------------------------------------------
// prep A: blocks 0..127 pack weights into MFMA B-frag layout (bf16);
//         blocks 128..159 per-block histogram slabs + init perm/srid.
// ---------------------------------------------------------------------------
__global__ void kprep_a(const int* __restrict__ rule_ids,
                        const float* __restrict__ shared_in,
                        const float* __restrict__ shared_out,
                        const float* __restrict__ rule_in,
                        const float* __restrict__ rule_out,
                        unsigned short* __restrict__ ssb,   // [64k32][3nf][64][8]
                        unsigned short* __restrict__ sob,   // [128CF][2kc][64][8]
                        unsigned short* __restrict__ rinf,  // [256][2half][64][8]
                        unsigned short* __restrict__ rof,   // [256][4cf][64][8]
                        int* __restrict__ ghist_part,
                        int* __restrict__ perm_p,
                        int* __restrict__ srid_p)
{
    if (blockIdx.x < 128) {
        const int tid = blockIdx.x * 256 + threadIdx.x;
        const int stride = 128 * 256;
        for (int idx = tid; idx < 64 * 3 * 512; idx += stride) {
            int ch = idx / 1536, rem = idx - ch * 1536;
            int nf = rem / 512;
            int l = (rem >> 3) & 63, j = idx & 7;
            int k = ch * 32 + ((l >> 4) << 3) + j;
            int col = nf * 16 + (l & 15);
            ssb[idx] = (col < SR) ? (unsigned short)f2bs(shared_in[(size_t)k * SR + col]) : 0;
        }
        for (int idx = tid; idx < 128 * 2 * 512; idx += stride) {
            int CF = idx >> 10;
            int kc = (idx >> 9) & 1;
            int l = (idx >> 3) & 63, j = idx & 7;
            int k = kc * 32 + ((l >> 4) << 3) + j;
            int col = CF * 16 + (l & 15);
            sob[idx] = (k < SR) ? (unsigned short)f2bs(shared_out[(size_t)k * OUTF + col]) : 0;
        }
        for (int idx = tid; idx < NRULE * 2 * 512; idx += stride) {
            int rid = idx >> 10;
            int half = (idx >> 9) & 1;
            int l = (idx >> 3) & 63, j = idx & 7;
            int r = l & 15;
            int s = half * 32 + ((l >> 4) << 3) + j;
            rinf[idx] = (r < RANK) ? (unsigned short)f2bs(rule_in[(size_t)rid * 512 + s * RANK + r]) : 0;
        }
        for (int idx = tid; idx < NRULE * 4 * 512; idx += stride) {
            int rid = idx >> 11;
            int cf = (idx >> 9) & 3;
            int l = (idx >> 3) & 63, j = idx & 7;
            int k = ((l >> 4) << 3) + j;
            int c = cf * 16 + (l & 15);
            rof[idx] = (k < RANK) ? (unsigned short)f2bs(rule_out[(size_t)rid * 512 + k * BLK + c]) : 0;
        }
    } else {
        __shared__ int lh[NRULE];
        const int tid = threadIdx.x;
        const int hb = blockIdx.x - 128;
        lh[tid] = 0;
        __syncthreads();
        const int base = hb * 512;
        atomicAdd(&lh[rule_ids[base + tid]], 1);
        atomicAdd(&lh[rule_ids[base + 256 + tid]], 1);
        __syncthreads();
        ghist_part[hb * NRULE + tid] = lh[tid];
        for (int j = tid; j < MAXSLOT / 32; j += 256) {
            int idx = hb * (MAXSLOT / 32) + j;
            perm_p[idx] = -1;
            srid_p[idx] = 0;
        }
    }
}

__global__ void kprep_scan(const int* __restrict__ ghist_part,
                           const float* __restrict__ logits,
                           int* __restrict__ gcnt,
                           int* __restrict__ srid_p,
                           float* __restrict__ sel_t,
                           int* __restrict__ ntot)
{
    __shared__ int sc[NRULE];
    const int tid = threadIdx.x;
    int h = 0;
#pragma unroll
    for (int b = 0; b < NHIST; ++b) h += ghist_part[b * NRULE + tid];
    const int pd = (h + 15) & ~15;
    sc[tid] = pd;
    for (int off = 1; off < NRULE; off <<= 1) {
        __syncthreads();
        int v = (tid >= off) ? sc[tid - off] : 0;
        __syncthreads();
        sc[tid] += v;
    }
    __syncthreads();
    const int excl = sc[tid] - pd;
    gcnt[tid] = excl;
    for (int q = h; q < pd; ++q) srid_p[excl + q] = tid;
    if (tid == NRULE - 1) *ntot = sc[tid];
    const float invT = 5.65685424949238f;
    const float* __restrict__ lg = logits + (size_t)tid * NBLK;
    float m = -1e30f;
    for (int b = 0; b < NBLK; ++b) m = fmaxf(m, lg[b] * invT);
    float s = 0.0f;
    for (int b = 0; b < NBLK; ++b) s += expf(lg[b] * invT - m);
    const float inv = 1.0f / s;
    for (int b = 0; b < NBLK; ++b)
        sel_t[(size_t)tid * NBLK + b] = expf(lg[b] * invT - m) * inv;
}

__global__ void kprep_scatter(const int* __restrict__ rule_ids,
                              int* __restrict__ gcnt,
                              int* __restrict__ perm_p,
                              int* __restrict__ srid_p)
{
    const int i = blockIdx.x * 256 + threadIdx.x;
    const int r = rule_ids[i];
    const int p = atomicAdd(&gcnt[r], 1);
    perm_p[p] = i;
    srid_p[p] = r;
}

// ---------------------------------------------------------------------------
// kmain: 16 slots, 256 thr = 4 waves.
// Phase 1: x staged in QUARTERS (512 cols = 32 KB f32) via 8 fire-and-forget
//   global_load_lds volleys per thread, double-buffered; ONE __syncthreads
//   per quarter (4 per tile, was 32). 32 KB DMA in flight per round -> the
//   drain is BW-bound, not latency-bound. Wave w owns whole chunks {w, w+4}
//   of each quarter -> hidden wave-local (no cross-wave merge).
//   LDS layout (from the DMA's linear dest): cell(row,unit16B) =
//   (u>>4)*4096 + ((u>>2)&3)*1024 + (u&3)*256 + row*16  -> fragment reads
//   are 256 B-contiguous per 16 lanes (conflict-free), no XOR needed.
// Merge: tred overlays dead x buffers; reduce -> t_bf (bf16, K-padded).
// Phase 2: wave w covers col-quarter [512w, +512); R12's SBAR ring,
//   predicated stores. LDS 74.5 KB -> 2 blocks/CU.
// ---------------------------------------------------------------------------
__global__ __launch_bounds__(256, 2)
void kmain(const float* __restrict__ x,
           const int* __restrict__ perm_p,
           const int* __restrict__ srid_p,
           const unsigned short* __restrict__ ssb,
           const unsigned short* __restrict__ sob,
           const unsigned short* __restrict__ rinf,
           const unsigned short* __restrict__ rof,
           const float* __restrict__ sel_t,
           const int* __restrict__ ntot,
           float* __restrict__ out)
{
    __shared__ __align__(16) char xq[2][32768];               // 64 KB dbuf
    __shared__ __align__(16) unsigned short hs_lds[16][264];  // 8.25 KB
    __shared__ __align__(16) unsigned short t_bf[16][72];     // 2.25 KB

#define TRD(W, SL, C) (((float*)xq)[((W) * 16 + (SL)) * 52 + (C)])

    const int slot0 = blockIdx.x * 16;
    if (slot0 >= *ntot) return;

    const int tid  = threadIdx.x;       // 0..255
    const int lane = tid & 63;
    const int w    = tid >> 6;          // wave 0..3
    const int row_l = lane & 15, grp = lane >> 4;

    const int rid_u = __builtin_amdgcn_readfirstlane(srid_p[slot0]);

    // staging source: thread handles row (tid&15), unit (tid>>4)+16v
    int tok = perm_p[slot0 + (tid & 15)];  if (tok < 0) tok = 0;
    const char* gsrc = (const char*)(x + (size_t)tok * INF) + ((tid >> 4) << 4);

#define STAGEQ(Q) do { \
        char* lb = (char*)xq + (((Q) & 1) << 15) + (w << 10); \
        const size_t go = (size_t)(Q) * 2048; \
        _Pragma("unroll") \
        for (int v = 0; v < 8; ++v) \
            __builtin_amdgcn_global_load_lds((GU32*)(gsrc + go + v * 256), \
                                             (LU32*)(lb + v * 4096), 16, 0, 0); \
    } while (0)

    const bf16x8 ri0 = *(const bf16x8*)(rinf + ((size_t)rid_u * 2 + 0) * 512 + lane * 8);
    const bf16x8 ri1 = *(const bf16x8*)(rinf + ((size_t)rid_u * 2 + 1) * 512 + lane * 8);

    f32x4 aT0 = {0.f, 0.f, 0.f, 0.f};
    f32x4 aT1 = {0.f, 0.f, 0.f, 0.f};
    f32x4 aT2 = {0.f, 0.f, 0.f, 0.f};

    STAGEQ(0);
    __syncthreads();

#pragma unroll
    for (int q = 0; q < 4; ++q) {
        if (q < 3) STAGEQ(q + 1);       // 32 KB fire-and-forget, drains at the
                                        // barrier AFTER this quarter's compute
        const char* xb = (const char*)xq + ((q & 1) << 15);
#pragma unroll
        for (int cc = 0; cc < 2; ++cc) {
            const int c_local = (cc << 2) + w;   // w, w+4
            const int c = (q << 3) + c_local;    // global 64-col chunk
            f32x4 aH = {0.f, 0.f, 0.f, 0.f};
#pragma unroll
            for (int s = 0; s < 2; ++s) {
                const int bidx = c_local * 4096 + (2 * s + (grp >> 1)) * 1024
                               + (grp & 1) * 512 + row_l * 16;
                const float4 fa = *(const float4*)(xb + bidx);
                const float4 fb = *(const float4*)(xb + bidx + 256);
                const bf16x8 af = cvt8(fa, fb);
                const unsigned short* __restrict__ sp =
                    ssb + (size_t)(c * 2 + s) * 1536 + lane * 8;
                aT0 = MFMA(af, *(const bf16x8*)(sp),        aT0, 0, 0, 0);
                aT1 = MFMA(af, *(const bf16x8*)(sp + 512),  aT1, 0, 0, 0);
                aT2 = MFMA(af, *(const bf16x8*)(sp + 1024), aT2, 0, 0, 0);
                aH  = MFMA(af, s ? ri1 : ri0, aH, 0, 0, 0);
            }
            const float sel = sel_t[(size_t)rid_u * NBLK + c];
            if (row_l < RANK) {
#pragma unroll
                for (int q4 = 0; q4 < 4; ++q4)
                    hs_lds[(grp << 2) + q4][c * 8 + row_l] =
                        (unsigned short)f2bs(aH[q4] * sel);
            }
        }
        __syncthreads();                // DMA(q+1) landed; buf reads done
    }

    // ---- t partials -> tred (xq overlay), reduce 4 waves -> t_bf ----------
#pragma unroll
    for (int q4 = 0; q4 < 4; ++q4) {
        const int sl = (grp << 2) + q4;
        TRD(w, sl, row_l)      = aT0[q4];
        TRD(w, sl, 16 + row_l) = aT1[q4];
        TRD(w, sl, 32 + row_l) = aT2[q4];
    }
    __syncthreads();
    {
        const int sl = tid >> 4;        // 0..15
        const int c0 = (tid & 15) << 2; // 0..60
        s16x4 v = {0, 0, 0, 0};
        if (c0 < 48) {
#pragma unroll
            for (int j = 0; j < 4; ++j) {
                const float sm = TRD(0, sl, c0 + j) + TRD(1, sl, c0 + j)
                               + TRD(2, sl, c0 + j) + TRD(3, sl, c0 + j);
                v[j] = f2bs(sm);
            }
        }
        *(s16x4*)(&t_bf[sl][c0]) = v;
    }
    __syncthreads();

    // ===== phase 2: out = t@shared_out + hs@rule_out =======================
    {
        const int p = w;                // col-quarter: [p*512, +512)
        const bf16x8 at0 = *(const bf16x8*)(&t_bf[row_l][grp << 3]);
        const bf16x8 at1 = *(const bf16x8*)(&t_bf[row_l][32 + (grp << 3)]);

        bf16x8 rfv[4];
#pragma unroll
        for (int i = 0; i < 4; ++i)
            rfv[i] = *(const bf16x8*)(rof + ((size_t)rid_u * 4 + i) * 512 + lane * 8);

        const int4 pv = *(const int4*)(perm_p + slot0 + (grp << 2));
        float* const orow0 = out + (size_t)(pv.x < 0 ? 0 : pv.x) * OUTF;
        float* const orow1 = out + (size_t)(pv.y < 0 ? 0 : pv.y) * OUTF;
        float* const orow2 = out + (size_t)(pv.z < 0 ? 0 : pv.z) * OUTF;
        float* const orow3 = out + (size_t)(pv.w < 0 ? 0 : pv.w) * OUTF;

        const int CF0 = p * 32;
        const int bb0 = p * 8;
        const unsigned short* __restrict__ sobw = sob + (size_t)CF0 * 1024 + lane * 8;

        bf16x8 sb[4][2];
        bf16x8 ah[2];
        const bf16x8 zz = {0, 0, 0, 0, 0, 0, 0, 0};

#define LOADQ(SL, QI) do { \
        const unsigned short* _sp = sobw + (size_t)(QI) * 1024; \
        sb[SL][0] = *(const bf16x8*)(_sp); \
        sb[SL][1] = *(const bf16x8*)(_sp + 512); \
    } while (0)
#define LOADA(SL, BI) do { \
        ah[SL] = zz; \
        if (lane < 16) \
            ah[SL] = *(const bf16x8*)(&hs_lds[lane][(bb0 + (BI)) * 8]); \
    } while (0)

        LOADQ(0, 0); LOADQ(1, 1); LOADQ(2, 2);
        LOADA(0, 0);
        SBAR();

#pragma unroll
        for (int qi = 0; qi < 32; ++qi) {
            if (qi < 29) LOADQ((qi + 3) & 3, qi + 3);
            if ((qi & 3) == 0 && qi < 28) LOADA(((qi >> 2) + 1) & 1, (qi >> 2) + 1);
            SBAR();
            f32x4 acc = {0.f, 0.f, 0.f, 0.f};
            acc = MFMA(at0, sb[qi & 3][0], acc, 0, 0, 0);
            acc = MFMA(at1, sb[qi & 3][1], acc, 0, 0, 0);
            acc = MFMA(ah[(qi >> 2) & 1], rfv[qi & 3], acc, 0, 0, 0);
            const int col = ((CF0 + qi) << 4) + row_l;
            if (pv.x >= 0) orow0[col] = acc[0];
            if (pv.y >= 0) orow1[col] = acc[1];
            if (pv.z >= 0) orow2[col] = acc[2];
            if (pv.w >= 0) orow3[col] = acc[3];
            SBAR();
        }
#undef LOADQ
#undef LOADA
    }
}

extern "C" void kernel_launch(void* const* d_in, const int* in_sizes, int n_in,
                              void* d_out, int out_size, void* d_ws, size_t ws_size,
                              hipStream_t stream)
{
    const float* x          = (const float*)d_in[0];
    const int*   rule_ids   = (const int*)  d_in[1];
    const float* shared_in  = (const float*)d_in[2];
    const float* shared_out = (const float*)d_in[3];
    const float* rule_in    = (const float*)d_in[4];
    const float* rule_out   = (const float*)d_in[5];
    const float* logits     = (const float*)d_in[6];
    float* out = (float*)d_out;

    char* p = (char*)d_ws;
    auto carve = [&p](size_t bytes) {
        char* r = p;
        p += (bytes + 255) & ~(size_t)255;
        return r;
    };
    int*            perm_p = (int*)carve(MAXSLOT * 4);
    int*            srid_p = (int*)carve(MAXSLOT * 4);
    unsigned short* ssb    = (unsigned short*)carve(64 * 3 * 512 * 2);
    unsigned short* sob    = (unsigned short*)carve(128 * 2 * 512 * 2);
    unsigned short* rinf   = (unsigned short*)carve((size_t)NRULE * 2 * 512 * 2);
    unsigned short* rof    = (unsigned short*)carve((size_t)NRULE * 4 * 512 * 2);
    float*          sel_t  = (float*)carve((size_t)NRULE * NBLK * 4);
    int*            ghistp = (int*)carve((size_t)NHIST * NRULE * 4);
    int*            gcnt   = (int*)carve(NRULE * 4);
    int*            ntot   = (int*)carve(4);

    kprep_a<<<dim3(160), dim3(256), 0, stream>>>(
        rule_ids, shared_in, shared_out, rule_in, rule_out,
        ssb, sob, rinf, rof, ghistp, perm_p, srid_p);
    kprep_scan<<<dim3(1), dim3(256), 0, stream>>>(
        ghistp, logits, gcnt, srid_p, sel_t, ntot);
    kprep_scatter<<<dim3(64), dim3(256), 0, stream>>>(
        rule_ids, gcnt, perm_p, srid_p);
    kmain<<<dim3(NTILE16), dim3(256), 0, stream>>>(
        x, perm_p, srid_p, ssb, sob, rinf, rof, sel_t, ntot, out);
}

// Round 16
// 101.706 us; speedup vs baseline: 1.0936x; 1.0936x over previous
//
#include <hip/hip_runtime.h>
#include <hip/hip_bf16.h>
#include <math.h>

#define NTOK  16384
#define INF   2048
#define OUTF  2048
#define SR    45
#define RANK  8
#define BLK   64
#define NBLK  32
#define NRULE 256
#define NHIST 32
#define MAXSLOT (NTOK + NRULE * 15)   // 20224
#define NTILE16 (MAXSLOT / 16)        // 1264 tiles of 16 slots

typedef __attribute__((ext_vector_type(8))) short bf16x8;
typedef __attribute__((ext_vector_type(4))) float f32x4;
typedef __attribute__((ext_vector_type(4))) short s16x4;

typedef const __attribute__((address_space(1))) unsigned int GU32;
typedef __attribute__((address_space(3))) unsigned int LU32;

#define MFMA __builtin_amdgcn_mfma_f32_16x16x32_bf16
#define SBAR() __builtin_amdgcn_sched_barrier(0)

#define VMCNT(n) do { asm volatile("s_waitcnt vmcnt(" #n ")" ::: "memory"); \
                      __builtin_amdgcn_sched_barrier(0); } while (0)
#define GLOAD(dst, ptr) \
    asm volatile("global_load_dwordx4 %0, %1, off" : "=v"(dst) : "v"(ptr) : "memory")

__device__ inline short f2bs(float f) {
    __hip_bfloat16 h = __float2bfloat16(f);
    return *reinterpret_cast<short*>(&h);
}
__device__ inline float bs2f(unsigned short s) {
    union { unsigned u; float f; } v; v.u = ((unsigned)s) << 16; return v.f;
}
__device__ inline bf16x8 cvt8(const float4& a, const float4& b) {
    bf16x8 r;
    r[0] = f2bs(a.x); r[1] = f2bs(a.y); r[2] = f2bs(a.z); r[3] = f2bs(a.w);
    r[4] = f2bs(b.x); r[5] = f2bs(b.y); r[6] = f2bs(b.z); r[7] = f2bs(b.w);
    return r;
}

// ---------------------------------------------------------------------------
// prep A: blocks 0..127 pack weights into MFMA B-frag layout (bf16);
//         blocks 128..159 per-block histogram slabs + init perm/srid.
// ---------------------------------------------------------------------------
__global__ void kprep_a(const int* __restrict__ rule_ids,
                        const float* __restrict__ shared_in,
                        const float* __restrict__ shared_out,
                        const float* __restrict__ rule_in,
                        const float* __restrict__ rule_out,
                        unsigned short* __restrict__ ssb,   // [64k32][3nf][64][8]
                        unsigned short* __restrict__ sob,   // [128CF][2kc][64][8]
                        unsigned short* __restrict__ rinf,  // [256][2half][64][8]
                        unsigned short* __restrict__ rof,   // [256][4cf][64][8]
                        int* __restrict__ ghist_part,
                        int* __restrict__ perm_p,
                        int* __restrict__ srid_p)
{
    if (blockIdx.x < 128) {
        const int tid = blockIdx.x * 256 + threadIdx.x;
        const int stride = 128 * 256;
        for (int idx = tid; idx < 64 * 3 * 512; idx += stride) {
            int ch = idx / 1536, rem = idx - ch * 1536;
            int nf = rem / 512;
            int l = (rem >> 3) & 63, j = idx & 7;
            int k = ch * 32 + ((l >> 4) << 3) + j;
            int col = nf * 16 + (l & 15);
            ssb[idx] = (col < SR) ? (unsigned short)f2bs(shared_in[(size_t)k * SR + col]) : 0;
        }
        for (int idx = tid; idx < 128 * 2 * 512; idx += stride) {
            int CF = idx >> 10;
            int kc = (idx >> 9) & 1;
            int l = (idx >> 3) & 63, j = idx & 7;
            int k = kc * 32 + ((l >> 4) << 3) + j;
            int col = CF * 16 + (l & 15);
            sob[idx] = (k < SR) ? (unsigned short)f2bs(shared_out[(size_t)k * OUTF + col]) : 0;
        }
        for (int idx = tid; idx < NRULE * 2 * 512; idx += stride) {
            int rid = idx >> 10;
            int half = (idx >> 9) & 1;
            int l = (idx >> 3) & 63, j = idx & 7;
            int r = l & 15;
            int s = half * 32 + ((l >> 4) << 3) + j;
            rinf[idx] = (r < RANK) ? (unsigned short)f2bs(rule_in[(size_t)rid * 512 + s * RANK + r]) : 0;
        }
        for (int idx = tid; idx < NRULE * 4 * 512; idx += stride) {
            int rid = idx >> 11;
            int cf = (idx >> 9) & 3;
            int l = (idx >> 3) & 63, j = idx & 7;
            int k = ((l >> 4) << 3) + j;
            int c = cf * 16 + (l & 15);
            rof[idx] = (k < RANK) ? (unsigned short)f2bs(rule_out[(size_t)rid * 512 + k * BLK + c]) : 0;
        }
    } else {
        __shared__ int lh[NRULE];
        const int tid = threadIdx.x;
        const int hb = blockIdx.x - 128;
        lh[tid] = 0;
        __syncthreads();
        const int base = hb * 512;
        atomicAdd(&lh[rule_ids[base + tid]], 1);
        atomicAdd(&lh[rule_ids[base + 256 + tid]], 1);
        __syncthreads();
        ghist_part[hb * NRULE + tid] = lh[tid];
        for (int j = tid; j < MAXSLOT / 32; j += 256) {
            int idx = hb * (MAXSLOT / 32) + j;
            perm_p[idx] = -1;
            srid_p[idx] = 0;
        }
    }
}

__global__ void kprep_scan(const int* __restrict__ ghist_part,
                           const float* __restrict__ logits,
                           int* __restrict__ gcnt,
                           int* __restrict__ srid_p,
                           float* __restrict__ sel_t,
                           int* __restrict__ ntot)
{
    __shared__ int sc[NRULE];
    const int tid = threadIdx.x;
    int h = 0;
#pragma unroll
    for (int b = 0; b < NHIST; ++b) h += ghist_part[b * NRULE + tid];
    const int pd = (h + 15) & ~15;
    sc[tid] = pd;
    for (int off = 1; off < NRULE; off <<= 1) {
        __syncthreads();
        int v = (tid >= off) ? sc[tid - off] : 0;
        __syncthreads();
        sc[tid] += v;
    }
    __syncthreads();
    const int excl = sc[tid] - pd;
    gcnt[tid] = excl;
    for (int q = h; q < pd; ++q) srid_p[excl + q] = tid;
    if (tid == NRULE - 1) *ntot = sc[tid];
    const float invT = 5.65685424949238f;
    const float* __restrict__ lg = logits + (size_t)tid * NBLK;
    float m = -1e30f;
    for (int b = 0; b < NBLK; ++b) m = fmaxf(m, lg[b] * invT);
    float s = 0.0f;
    for (int b = 0; b < NBLK; ++b) s += expf(lg[b] * invT - m);
    const float inv = 1.0f / s;
    for (int b = 0; b < NBLK; ++b)
        sel_t[(size_t)tid * NBLK + b] = expf(lg[b] * invT - m) * inv;
}

__global__ void kprep_scatter(const int* __restrict__ rule_ids,
                              int* __restrict__ gcnt,
                              int* __restrict__ perm_p,
                              int* __restrict__ srid_p)
{
    const int i = blockIdx.x * 256 + threadIdx.x;
    const int r = rule_ids[i];
    const int p = atomicAdd(&gcnt[r], 1);
    perm_p[p] = i;
    srid_p[p] = r;
}

// ---------------------------------------------------------------------------
// k1: grid = tile x K-half (2528 blocks), 128 thr = 2 waves.
// Each wave owns 8 WHOLE 64-col chunks -> hidden wave-local, staging
// wave-private (global_load_lds into its own 2x4KB ring), ZERO barriers in
// the hot loop. All loop VMEM is manual (DMA + asm weight loads) -> exact
// per-wave vmcnt(10). LDS 20KB -> 8 blocks/CU; grid -> ~20 waves/CU.
// Outputs: t_part[tile][kh][tcol 64][slot 16] bf16; hs[slot][32][8] bf16.
// ---------------------------------------------------------------------------
__global__ __launch_bounds__(128, 4)
void k1(const float* __restrict__ x,
        const int* __restrict__ perm_p,
        const int* __restrict__ srid_p,
        const unsigned short* __restrict__ ssb,
        const unsigned short* __restrict__ rinf,
        const float* __restrict__ sel_t,
        const int* __restrict__ ntot,
        unsigned short* __restrict__ t_part,
        unsigned short* __restrict__ hs)
{
    __shared__ __align__(16) char xq[16384];                 // [wave][2 slot][4KB]
    __shared__ __align__(16) unsigned short hs_st[2][16][8][8]; // [w][slot][ci][r] 4KB

#define TRD(W, SL, C) (((float*)xq)[((W) * 16 + (SL)) * 48 + (C)])

    const int bid  = blockIdx.x;
    const int tile = bid >> 1, kh = bid & 1;
    const int slot0 = tile * 16;
    if (slot0 >= *ntot) return;

    const int tid  = threadIdx.x;
    const int lane = tid & 63;
    const int w    = tid >> 6;
    const int row_l = lane & 15, grp = lane >> 4;
    const int cbase = kh * 16 + w * 8;        // wave's first chunk

    const int rid_u = __builtin_amdgcn_readfirstlane(srid_p[slot0]);

    // per-lane staging sources: instr v stages rows 4v..4v+3, unit lane&15
    const char* gsrc0; const char* gsrc1; const char* gsrc2; const char* gsrc3;
    {
        const int u = lane & 15;
        const char* t[4];
#pragma unroll
        for (int v = 0; v < 4; ++v) {
            const int row = 4 * v + (lane >> 4);
            int tok = perm_p[slot0 + row];
            if (tok < 0) tok = 0;
            t[v] = (const char*)(x + (size_t)tok * INF) + ((u ^ (row & 7)) << 4);
        }
        gsrc0 = t[0]; gsrc1 = t[1]; gsrc2 = t[2]; gsrc3 = t[3];
    }

    const bf16x8 ri0 = *(const bf16x8*)(rinf + ((size_t)rid_u * 2 + 0) * 512 + lane * 8);
    const bf16x8 ri1 = *(const bf16x8*)(rinf + ((size_t)rid_u * 2 + 1) * 512 + lane * 8);
    float sel8[8];
#pragma unroll
    for (int ci = 0; ci < 8; ++ci)
        sel8[ci] = sel_t[(size_t)rid_u * NBLK + cbase + ci];

    // ds_read byte offsets (XOR-swizzled) within one 4KB slot
    const int swz = row_l & 7;
    int offs[2][2];
#pragma unroll
    for (int s = 0; s < 2; ++s)
#pragma unroll
        for (int e = 0; e < 2; ++e)
            offs[s][e] = row_l * 256 + (((s * 8 + grp * 2 + e) ^ swz) << 4);
    const int off00 = offs[0][0], off01 = offs[0][1];
    const int off10 = offs[1][0], off11 = offs[1][1];

    f32x4 aT0 = {0.f, 0.f, 0.f, 0.f};
    f32x4 aT1 = {0.f, 0.f, 0.f, 0.f};
    f32x4 aT2 = {0.f, 0.f, 0.f, 0.f};
    bf16x8 wreg[2][6];

    char* const xw = xq + (w << 13);          // wave's 8KB region

#define STAGE(SL, CI) do { \
        char* _lb = xw + ((SL) << 12); \
        const size_t _o = (size_t)(cbase + (CI)) << 8; \
        __builtin_amdgcn_global_load_lds((GU32*)(gsrc0 + _o), (LU32*)_lb,          16, 0, 0); \
        __builtin_amdgcn_global_load_lds((GU32*)(gsrc1 + _o), (LU32*)(_lb + 1024), 16, 0, 0); \
        __builtin_amdgcn_global_load_lds((GU32*)(gsrc2 + _o), (LU32*)(_lb + 2048), 16, 0, 0); \
        __builtin_amdgcn_global_load_lds((GU32*)(gsrc3 + _o), (LU32*)(_lb + 3072), 16, 0, 0); \
    } while (0)

#define WLOAD(SL, CI) do { \
        const unsigned short* _w0 = ssb + (size_t)((cbase + (CI)) * 2) * 1536 + lane * 8; \
        GLOAD(wreg[SL][0], _w0); \
        GLOAD(wreg[SL][1], _w0 + 512); \
        GLOAD(wreg[SL][2], _w0 + 1024); \
        GLOAD(wreg[SL][3], _w0 + 1536); \
        GLOAD(wreg[SL][4], _w0 + 2048); \
        GLOAD(wreg[SL][5], _w0 + 2560); \
    } while (0)

    VMCNT(0);                                 // ledger starts clean

    STAGE(0, 0); WLOAD(0, 0);                 // batch0: 10 ops
    STAGE(1, 1); WLOAD(1, 1);                 // batch1: 10 ops

#pragma unroll
    for (int ci = 0; ci < 8; ++ci) {
        if (ci < 7) { VMCNT(10); } else { VMCNT(0); }   // batch(ci) landed
        const int sl = ci & 1;
        const char* xb = xw + (sl << 12);
        f32x4 aH = {0.f, 0.f, 0.f, 0.f};
        {
            const float4 fa0 = *(const float4*)(xb + off00);
            const float4 fa1 = *(const float4*)(xb + off01);
            const bf16x8 af0 = cvt8(fa0, fa1);
            aT0 = MFMA(af0, wreg[sl][0], aT0, 0, 0, 0);
            aT1 = MFMA(af0, wreg[sl][1], aT1, 0, 0, 0);
            aT2 = MFMA(af0, wreg[sl][2], aT2, 0, 0, 0);
            aH  = MFMA(af0, ri0, aH, 0, 0, 0);
            const float4 fb0 = *(const float4*)(xb + off10);
            const float4 fb1 = *(const float4*)(xb + off11);
            const bf16x8 af1 = cvt8(fb0, fb1);
            aT0 = MFMA(af1, wreg[sl][3], aT0, 0, 0, 0);
            aT1 = MFMA(af1, wreg[sl][4], aT1, 0, 0, 0);
            aT2 = MFMA(af1, wreg[sl][5], aT2, 0, 0, 0);
            aH  = MFMA(af1, ri1, aH, 0, 0, 0);
        }
        if (row_l < RANK) {                   // hidden -> wave-local LDS stage
#pragma unroll
            for (int q = 0; q < 4; ++q)
                hs_st[w][(grp << 2) + q][ci][row_l] =
                    (unsigned short)f2bs(aH[q] * sel8[ci]);
        }
        if (ci < 6) { STAGE(sl, ci + 2); WLOAD(sl, ci + 2); }
    }

    // ---- dump hs (wave-local; compiler inserts lgkm waits) -----------------
    {
        const unsigned short* src = &hs_st[w][0][0][0] + lane * 16;
        const bf16x8 h0 = *(const bf16x8*)(src);
        const bf16x8 h1 = *(const bf16x8*)(src + 8);
        unsigned short* dst = hs + ((size_t)(slot0 + (lane >> 2))) * 256
                            + cbase * 8 + (lane & 3) * 16;
        *(bf16x8*)(dst)     = h0;
        *(bf16x8*)(dst + 8) = h1;
    }

    // ---- t partials -> tred (xq overlay), reduce 2 waves, write bf16 ------
    __syncthreads();                          // all xq reads done
#pragma unroll
    for (int q = 0; q < 4; ++q) {
        const int sl = (grp << 2) + q;
        TRD(w, sl, row_l)      = aT0[q];
        TRD(w, sl, 16 + row_l) = aT1[q];
        TRD(w, sl, 32 + row_l) = aT2[q];
    }
    __syncthreads();
    {
        const int tcol = tid >> 1;            // 0..63
        const int s8   = (tid & 1) * 8;
        bf16x8 vv;
#pragma unroll
        for (int j = 0; j < 8; ++j) {
            float v = 0.f;
            if (tcol < 48)
                v = TRD(0, s8 + j, tcol) + TRD(1, s8 + j, tcol);
            vv[j] = f2bs(v);
        }
        *(bf16x8*)(t_part + ((size_t)(tile * 2 + kh) * 64 + tcol) * 16 + s8) = vv;
    }
}

// ---------------------------------------------------------------------------
// k2: grid = tile x col-half (2528 blocks), 128 thr = 2 waves (col-quarters).
// Stage t (sum 2 bf16 halves) -> t_bf LDS; then R14's proven 32-qi phase-2
// ring; hs read directly from global (L3-hot); predicated stores.
// LDS 2.25KB -> ~20 waves/CU of store streaming.
// ---------------------------------------------------------------------------
__global__ __launch_bounds__(128, 4)
void k2(const unsigned short* __restrict__ t_part,
        const unsigned short* __restrict__ hs,
        const int* __restrict__ perm_p,
        const int* __restrict__ srid_p,
        const unsigned short* __restrict__ sob,
        const unsigned short* __restrict__ rof,
        const int* __restrict__ ntot,
        float* __restrict__ out)
{
    __shared__ __align__(16) unsigned short t_bf[16][72];

    const int bid  = blockIdx.x;
    const int tile = bid >> 1, chf = bid & 1;
    const int slot0 = tile * 16;
    if (slot0 >= *ntot) return;

    const int tid  = threadIdx.x;
    const int lane = tid & 63;
    const int w    = tid >> 6;
    const int p    = chf * 2 + w;             // col-quarter 0..3
    const int row_l = lane & 15, grp = lane >> 4;

    const int rid_u = __builtin_amdgcn_readfirstlane(srid_p[slot0]);

    // stage t: sum the two K-half partials (bf16 -> f32 -> bf16)
    {
        const int slot = tid & 15, tc8 = tid >> 4;     // tc8: 0..7
        const unsigned short* t0 = t_part + ((size_t)(tile * 2 + 0) * 64) * 16;
        const unsigned short* t1 = t_part + ((size_t)(tile * 2 + 1) * 64) * 16;
        bf16x8 vv;
#pragma unroll
        for (int j = 0; j < 8; ++j) {
            const int tcol = tc8 * 8 + j;
            const float v = bs2f(t0[tcol * 16 + slot]) + bs2f(t1[tcol * 16 + slot]);
            vv[j] = f2bs(v);
        }
        *(bf16x8*)(&t_bf[slot][tc8 * 8]) = vv;
    }
    __syncthreads();

    const bf16x8 at0 = *(const bf16x8*)(&t_bf[row_l][grp << 3]);
    const bf16x8 at1 = *(const bf16x8*)(&t_bf[row_l][32 + (grp << 3)]);

    bf16x8 rfv[4];
#pragma unroll
    for (int i = 0; i < 4; ++i)
        rfv[i] = *(const bf16x8*)(rof + ((size_t)rid_u * 4 + i) * 512 + lane * 8);

    const int4 pv = *(const int4*)(perm_p + slot0 + (grp << 2));
    float* const orow0 = out + (size_t)(pv.x < 0 ? 0 : pv.x) * OUTF;
    float* const orow1 = out + (size_t)(pv.y < 0 ? 0 : pv.y) * OUTF;
    float* const orow2 = out + (size_t)(pv.z < 0 ? 0 : pv.z) * OUTF;
    float* const orow3 = out + (size_t)(pv.w < 0 ? 0 : pv.w) * OUTF;

    const int CF0 = p * 32;
    const int bb0 = p * 8;
    const unsigned short* __restrict__ sobw = sob + (size_t)CF0 * 1024 + lane * 8;
    const unsigned short* __restrict__ hsw  = hs + (size_t)(slot0 + (lane & 15)) * 256;

    bf16x8 sb[4][2];
    bf16x8 ah[2];
    const bf16x8 zz = {0, 0, 0, 0, 0, 0, 0, 0};

#define LOADQ(SL, QI) do { \
        const unsigned short* _sp = sobw + (size_t)(QI) * 1024; \
        sb[SL][0] = *(const bf16x8*)(_sp); \
        sb[SL][1] = *(const bf16x8*)(_sp + 512); \
    } while (0)
#define LOADA(SL, BI) do { \
        ah[SL] = zz; \
        if (lane < 16) \
            ah[SL] = *(const bf16x8*)(hsw + (size_t)(bb0 + (BI)) * 8); \
    } while (0)

    LOADQ(0, 0); LOADQ(1, 1); LOADQ(2, 2);
    LOADA(0, 0);
    SBAR();

#pragma unroll
    for (int qi = 0; qi < 32; ++qi) {
        if (qi < 29) LOADQ((qi + 3) & 3, qi + 3);
        if ((qi & 3) == 0 && qi < 28) LOADA(((qi >> 2) + 1) & 1, (qi >> 2) + 1);
        SBAR();
        f32x4 acc = {0.f, 0.f, 0.f, 0.f};
        acc = MFMA(at0, sb[qi & 3][0], acc, 0, 0, 0);
        acc = MFMA(at1, sb[qi & 3][1], acc, 0, 0, 0);
        acc = MFMA(ah[(qi >> 2) & 1], rfv[qi & 3], acc, 0, 0, 0);
        const int col = ((CF0 + qi) << 4) + row_l;
        if (pv.x >= 0) orow0[col] = acc[0];
        if (pv.y >= 0) orow1[col] = acc[1];
        if (pv.z >= 0) orow2[col] = acc[2];
        if (pv.w >= 0) orow3[col] = acc[3];
        SBAR();
    }
#undef LOADQ
#undef LOADA
}

extern "C" void kernel_launch(void* const* d_in, const int* in_sizes, int n_in,
                              void* d_out, int out_size, void* d_ws, size_t ws_size,
                              hipStream_t stream)
{
    const float* x          = (const float*)d_in[0];
    const int*   rule_ids   = (const int*)  d_in[1];
    const float* shared_in  = (const float*)d_in[2];
    const float* shared_out = (const float*)d_in[3];
    const float* rule_in    = (const float*)d_in[4];
    const float* rule_out   = (const float*)d_in[5];
    const float* logits     = (const float*)d_in[6];
    float* out = (float*)d_out;

    char* p = (char*)d_ws;
    auto carve = [&p](size_t bytes) {
        char* r = p;
        p += (bytes + 255) & ~(size_t)255;
        return r;
    };
    int*            perm_p = (int*)carve(MAXSLOT * 4);
    int*            srid_p = (int*)carve(MAXSLOT * 4);
    unsigned short* ssb    = (unsigned short*)carve(64 * 3 * 512 * 2);
    unsigned short* sob    = (unsigned short*)carve(128 * 2 * 512 * 2);
    unsigned short* rinf   = (unsigned short*)carve((size_t)NRULE * 2 * 512 * 2);
    unsigned short* rof    = (unsigned short*)carve((size_t)NRULE * 4 * 512 * 2);
    float*          sel_t  = (float*)carve((size_t)NRULE * NBLK * 4);
    int*            ghistp = (int*)carve((size_t)NHIST * NRULE * 4);
    int*            gcnt   = (int*)carve(NRULE * 4);
    int*            ntot   = (int*)carve(4);
    unsigned short* t_part = (unsigned short*)carve((size_t)NTILE16 * 2 * 64 * 16 * 2);
    unsigned short* hs     = (unsigned short*)carve((size_t)MAXSLOT * 256 * 2);

    kprep_a<<<dim3(160), dim3(256), 0, stream>>>(
        rule_ids, shared_in, shared_out, rule_in, rule_out,
        ssb, sob, rinf, rof, ghistp, perm_p, srid_p);
    kprep_scan<<<dim3(1), dim3(256), 0, stream>>>(
        ghistp, logits, gcnt, srid_p, sel_t, ntot);
    kprep_scatter<<<dim3(64), dim3(256), 0, stream>>>(
        rule_ids, gcnt, perm_p, srid_p);
    k1<<<dim3(NTILE16 * 2), dim3(128), 0, stream>>>(
        x, perm_p, srid_p, ssb, rinf, sel_t, ntot, t_part, hs);
    k2<<<dim3(NTILE16 * 2), dim3(128), 0, stream>>>(
        t_part, hs, perm_p, srid_p, sob, rof, ntot, out);
}